// Round 8
// baseline (234.145 us; speedup 1.0000x reference)
//
#include <hip/hip_runtime.h>
#include <math.h>

#define Dm 1024
#define Hn 16
#define HDn 64
#define Sn 1024

typedef __attribute__((ext_vector_type(8))) __bf16 bf16x8;
typedef __attribute__((ext_vector_type(4))) float floatx4;

__device__ __forceinline__ void async_ld16(void* lds, const void* g) {
    __builtin_amdgcn_global_load_lds(
        (const __attribute__((address_space(1))) void*)g,
        (__attribute__((address_space(3))) void*)lds,
        16, 0, 0);
}

// ---------------------------------------------------------------------------
// Prep kernel. grid (2048, 1, 8), 256 thr.
//  z 0..2 : fp32->bf16 cast of q/k/v (8 elems/thread)
//  z 3..6 : W [k][n] fp32 -> WT [n][k] bf16, 64x64 tiles (x < 256)
//  z 7    : zero d_out (2 float4/thread)
// ---------------------------------------------------------------------------
struct PrepArgs {
    const float* qkv[3];
    __bf16*      qkv_o[3];
    const float* W[4];
    __bf16*      WT[4];
    float*       out_zero;
};

__global__ __launch_bounds__(256) void prep_kernel(PrepArgs a)
{
    __shared__ float sT[64][65];
    const int z = blockIdx.z, x = blockIdx.x, tid = threadIdx.x;

    if (z < 3) {
        const float* src = a.qkv[z];
        __bf16* dst = a.qkv_o[z];
        const int lin = x * 256 + tid;
        const float4 v0 = ((const float4*)src)[lin * 2];
        const float4 v1 = ((const float4*)src)[lin * 2 + 1];
        bf16x8 o;
        o[0] = (__bf16)v0.x; o[1] = (__bf16)v0.y; o[2] = (__bf16)v0.z; o[3] = (__bf16)v0.w;
        o[4] = (__bf16)v1.x; o[5] = (__bf16)v1.y; o[6] = (__bf16)v1.z; o[7] = (__bf16)v1.w;
        ((bf16x8*)dst)[lin] = o;
    } else if (z < 7) {
        if (x >= 256) return;
        const float* W = a.W[z - 3];
        __bf16* O = a.WT[z - 3];
        const int bi = (x >> 4) * 64, bj = (x & 15) * 64;
        const int colr = tid & 63, rowg = tid >> 6;
        #pragma unroll
        for (int i = 0; i < 16; ++i) {
            const int kk = i * 4 + rowg;
            sT[kk][colr] = W[(size_t)(bi + kk) * Dm + bj + colr];
        }
        __syncthreads();
        #pragma unroll
        for (int i = 0; i < 16; ++i) {
            const int rn = i * 4 + rowg;
            O[(size_t)(bj + rn) * Dm + bi + colr] = (__bf16)sT[colr][rn];
        }
    } else {
        float4* o = (float4*)a.out_zero;
        const int i = (x * 256 + tid) * 2;
        const float4 zz = make_float4(0.f, 0.f, 0.f, 0.f);
        o[i] = zz;
        o[i + 1] = zz;
    }
}

// ---------------------------------------------------------------------------
// bf16 MFMA GEMM: 128x128 tile, BK=64 (32 MFMA/barrier), 4 waves x 64x64.
// global_load_lds width-16 staging, 8-chunk/row XOR swizzle (conflict-free
// b128: bank = 4*c, c = quad^(ks<<2)^(r&7), 8 lanes per c).
// XCD-aware block swizzle: XCD c owns m-tiles {4c..4c+3} x all n-tiles.
// layout 0: bf16 [B,H,S,HD]; 1: bf16 [B,H,HD,S]. blockIdx.z = instance.
// ---------------------------------------------------------------------------
struct GemmArgs {
    const __bf16* X[3];
    const __bf16* WT[3];
    const float*  bias[3];
    void*         out[3];
    int   layout[3];
    float esc[3];
};

__global__ __launch_bounds__(256) void gemm_bf16_kernel(GemmArgs args)
{
    __shared__ __align__(16) __bf16 sA[128 * 64];   // 16 KB
    __shared__ __align__(16) __bf16 sB[128 * 64];   // 16 KB

    const int z = blockIdx.z;
    const __bf16* __restrict__ Xb  = args.X[z];
    const __bf16* __restrict__ WTb = args.WT[z];
    const float*  __restrict__ bias = args.bias[z];
    void* __restrict__ outp = args.out[z];
    const int layout = args.layout[z];
    const float escale = args.esc[z];

    const int tid = threadIdx.x;
    const int id = blockIdx.x + (blockIdx.y << 3);
    const int bm = (((id & 7) << 2) | (id >> 6)) * 128;
    const int bn = ((id >> 3) & 7) * 128;

    const int lane = tid & 63;
    const int wave = tid >> 6;
    const int wm = (wave & 1) * 64;
    const int wn = (wave >> 1) * 64;
    const int l15 = lane & 15, quad = lane >> 4;

    floatx4 acc[4][4];
    #pragma unroll
    for (int mi = 0; mi < 4; ++mi)
        #pragma unroll
        for (int ni = 0; ni < 4; ++ni)
            acc[mi][ni] = (floatx4){0.f, 0.f, 0.f, 0.f};

    // staging: 1024 chunks per matrix per K-step; thread does 4 (sets j=0..3)
    const __bf16* gA[4];
    const __bf16* gB[4];
    char* lA[4];
    char* lB[4];
    #pragma unroll
    for (int j = 0; j < 4; ++j) {
        const int ci = tid + j * 256;
        const int r = ci >> 3, qc = (ci & 7) ^ (r & 7);
        gA[j] = Xb  + (size_t)(bm + r) * Dm + qc * 8;
        gB[j] = WTb + (size_t)(bn + r) * Dm + qc * 8;
        lA[j] = (char*)sA + (j * 256 + (tid & 192)) * 16;
        lB[j] = (char*)sB + (j * 256 + (tid & 192)) * 16;
    }

    for (int kt = 0; kt < Dm; kt += 64) {
        #pragma unroll
        for (int j = 0; j < 4; ++j) {
            async_ld16(lA[j], gA[j] + kt);
            async_ld16(lB[j], gB[j] + kt);
        }
        __syncthreads();

        #pragma unroll
        for (int ks = 0; ks < 2; ++ks) {
            bf16x8 af[4], bfr[4];
            #pragma unroll
            for (int mi = 0; mi < 4; ++mi) {
                const int r = wm + mi * 16 + l15;
                af[mi] = *(const bf16x8*)(sA + r * 64 +
                         ((((ks << 2) | quad) ^ (r & 7)) * 8));
            }
            #pragma unroll
            for (int ni = 0; ni < 4; ++ni) {
                const int r = wn + ni * 16 + l15;
                bfr[ni] = *(const bf16x8*)(sB + r * 64 +
                          ((((ks << 2) | quad) ^ (r & 7)) * 8));
            }
            #pragma unroll
            for (int mi = 0; mi < 4; ++mi)
                #pragma unroll
                for (int ni = 0; ni < 4; ++ni)
                    acc[mi][ni] = __builtin_amdgcn_mfma_f32_16x16x32_bf16(
                        af[mi], bfr[ni], acc[mi][ni], 0, 0, 0);
        }
        __syncthreads();
    }

    #pragma unroll
    for (int mi = 0; mi < 4; ++mi) {
        #pragma unroll
        for (int ni = 0; ni < 4; ++ni) {
            const int n = bn + wn + ni * 16 + l15;
            const float bv = bias[n];
            const int h = n >> 6, d = n & 63;
            #pragma unroll
            for (int reg = 0; reg < 4; ++reg) {
                const int m = bm + wm + mi * 16 + quad * 4 + reg;
                const int b = m >> 10, s = m & 1023;
                float v = fmaxf(acc[mi][ni][reg] + bv, 0.0f) * escale;
                if (layout == 0)
                    ((__bf16*)outp)[((size_t)(b * Hn + h) * 1024 + s) * 64 + d] = (__bf16)v;
                else
                    ((__bf16*)outp)[((size_t)(b * Hn + h) * 64 + d) * 1024 + s] = (__bf16)v;
            }
        }
    }
}

// ---------------------------------------------------------------------------
// Output GEMM, split-K=2, BK=64: z = K-half, 512 blocks (2/CU). fp32
// atomicAdd into pre-zeroed d_out (2 commutative adds -> deterministic).
// ---------------------------------------------------------------------------
__global__ __launch_bounds__(256) void gemm_splitk_kernel(
    const __bf16* __restrict__ Xb, const __bf16* __restrict__ WTb,
    const float* __restrict__ bias, float* __restrict__ outp)
{
    __shared__ __align__(16) __bf16 sA[128 * 64];
    __shared__ __align__(16) __bf16 sB[128 * 64];

    const int tid = threadIdx.x;
    const int kz = blockIdx.z;
    const int id = blockIdx.x + (blockIdx.y << 3);
    const int bm = (((id & 7) << 2) | (id >> 6)) * 128;
    const int bn = ((id >> 3) & 7) * 128;

    const int lane = tid & 63;
    const int wave = tid >> 6;
    const int wm = (wave & 1) * 64;
    const int wn = (wave >> 1) * 64;
    const int l15 = lane & 15, quad = lane >> 4;

    floatx4 acc[4][4];
    #pragma unroll
    for (int mi = 0; mi < 4; ++mi)
        #pragma unroll
        for (int ni = 0; ni < 4; ++ni)
            acc[mi][ni] = (floatx4){0.f, 0.f, 0.f, 0.f};

    const int kofs = kz * 512;
    const __bf16* gA[4];
    const __bf16* gB[4];
    char* lA[4];
    char* lB[4];
    #pragma unroll
    for (int j = 0; j < 4; ++j) {
        const int ci = tid + j * 256;
        const int r = ci >> 3, qc = (ci & 7) ^ (r & 7);
        gA[j] = Xb  + (size_t)(bm + r) * Dm + kofs + qc * 8;
        gB[j] = WTb + (size_t)(bn + r) * Dm + kofs + qc * 8;
        lA[j] = (char*)sA + (j * 256 + (tid & 192)) * 16;
        lB[j] = (char*)sB + (j * 256 + (tid & 192)) * 16;
    }

    for (int kt = 0; kt < 512; kt += 64) {
        #pragma unroll
        for (int j = 0; j < 4; ++j) {
            async_ld16(lA[j], gA[j] + kt);
            async_ld16(lB[j], gB[j] + kt);
        }
        __syncthreads();

        #pragma unroll
        for (int ks = 0; ks < 2; ++ks) {
            bf16x8 af[4], bfr[4];
            #pragma unroll
            for (int mi = 0; mi < 4; ++mi) {
                const int r = wm + mi * 16 + l15;
                af[mi] = *(const bf16x8*)(sA + r * 64 +
                         ((((ks << 2) | quad) ^ (r & 7)) * 8));
            }
            #pragma unroll
            for (int ni = 0; ni < 4; ++ni) {
                const int r = wn + ni * 16 + l15;
                bfr[ni] = *(const bf16x8*)(sB + r * 64 +
                          ((((ks << 2) | quad) ^ (r & 7)) * 8));
            }
            #pragma unroll
            for (int mi = 0; mi < 4; ++mi)
                #pragma unroll
                for (int ni = 0; ni < 4; ++ni)
                    acc[mi][ni] = __builtin_amdgcn_mfma_f32_16x16x32_bf16(
                        af[mi], bfr[ni], acc[mi][ni], 0, 0, 0);
        }
        __syncthreads();
    }

    #pragma unroll
    for (int mi = 0; mi < 4; ++mi) {
        #pragma unroll
        for (int ni = 0; ni < 4; ++ni) {
            const int n = bn + wn + ni * 16 + l15;
            const float bv = (kz == 0) ? bias[n] : 0.0f;
            #pragma unroll
            for (int reg = 0; reg < 4; ++reg) {
                const int m = bm + wm + mi * 16 + quad * 4 + reg;
                atomicAdd(outp + (size_t)m * 1024 + n, acc[mi][ni][reg] + bv);
            }
        }
    }
}

// ---------------------------------------------------------------------------
// Flash attention (verified): S = Q·K^T, no-max softmax (post-ReLU Q,K =>
// scores >= 0, bounded; Q pre-scaled by log2(e)/32), P via wave-private LDS,
// PV with 16x16x32 MFMA. 64-key tiles, double-buffered. XCD swizzle.
// ---------------------------------------------------------------------------
__global__ __launch_bounds__(256, 2) void flash_attn_kernel(
    const __bf16* __restrict__ Qh,  // [B,H,S,HD]  (pre-scaled by log2e/32)
    const __bf16* __restrict__ Kh,  // [B,H,S,HD]
    const __bf16* __restrict__ Vt,  // [B,H,HD,S]
    __bf16* __restrict__ ctx)       // [B,S,D]
{
    __shared__ __align__(16) char sKV[2][16384];   // per buf: K 8KB | V^T 8KB
    __shared__ __align__(16) __bf16 sP[4][32 * 64];

    const int tid = threadIdx.x;
    const int wave = tid >> 6, lane = tid & 63;
    const int l15 = lane & 15, quad = lane >> 4;

    const int id = blockIdx.x + (blockIdx.y << 3) + (blockIdx.z << 7);
    const int kk = id >> 3;
    const int bh = ((id & 7) << 3) | (kk & 7);
    const int b = bh >> 4, h = bh & 15;
    const int qb = (kk >> 3) * 128 + wave * 32;

    bf16x8 aQ[2][2];
    #pragma unroll
    for (int mi = 0; mi < 2; ++mi)
        #pragma unroll
        for (int ks = 0; ks < 2; ++ks)
            aQ[mi][ks] = *(const bf16x8*)(Qh +
                (size_t)(bh * Sn + qb + mi * 16 + l15) * 64 + ks * 32 + quad * 8);

    const int s0 = tid, s1 = tid + 256;
    const int r0 = s0 >> 3, q0c = (s0 & 7) ^ (r0 & 7);
    const int r1 = s1 >> 3, q1c = (s1 & 7) ^ (r1 & 7);
    const __bf16* gK0 = Kh + (size_t)(bh * Sn + r0) * 64 + q0c * 8;
    const __bf16* gK1 = Kh + (size_t)(bh * Sn + r1) * 64 + q1c * 8;
    const __bf16* gV0 = Vt + (size_t)(bh * 64 + r0) * Sn + q0c * 8;
    const __bf16* gV1 = Vt + (size_t)(bh * 64 + r1) * Sn + q1c * 8;
    const int wofs = (tid & 192) * 16;

    floatx4 oacc[2][4];
    #pragma unroll
    for (int mi = 0; mi < 2; ++mi)
        #pragma unroll
        for (int nf = 0; nf < 4; ++nf)
            oacc[mi][nf] = (floatx4){0.f, 0.f, 0.f, 0.f};
    float lsum[2][4];
    #pragma unroll
    for (int mi = 0; mi < 2; ++mi)
        #pragma unroll
        for (int r = 0; r < 4; ++r) lsum[mi][r] = 0.0f;

    __bf16* sPw = sP[wave];

    {
        char* bK = sKV[0];
        char* bV = sKV[0] + 8192;
        async_ld16(bK + wofs,        gK0);
        async_ld16(bK + 4096 + wofs, gK1);
        async_ld16(bV + wofs,        gV0);
        async_ld16(bV + 4096 + wofs, gV1);
    }

    int cur = 0;
    for (int it = 0; it < 16; ++it) {
        __syncthreads();

        if (it + 1 < 16) {
            const int t0n = (it + 1) * 64;
            char* bK = sKV[cur ^ 1];
            char* bV = sKV[cur ^ 1] + 8192;
            async_ld16(bK + wofs,        gK0 + (size_t)t0n * 64);
            async_ld16(bK + 4096 + wofs, gK1 + (size_t)t0n * 64);
            async_ld16(bV + wofs,        gV0 + t0n);
            async_ld16(bV + 4096 + wofs, gV1 + t0n);
        }

        const __bf16* sK = (const __bf16*)sKV[cur];
        const __bf16* sV = (const __bf16*)(sKV[cur] + 8192);

        floatx4 sc[2][4];
        #pragma unroll
        for (int mi = 0; mi < 2; ++mi)
            #pragma unroll
            for (int nf = 0; nf < 4; ++nf)
                sc[mi][nf] = (floatx4){0.f, 0.f, 0.f, 0.f};
        #pragma unroll
        for (int ks = 0; ks < 2; ++ks) {
            bf16x8 bK[4];
            #pragma unroll
            for (int nf = 0; nf < 4; ++nf) {
                const int n = nf * 16 + l15;
                bK[nf] = *(const bf16x8*)(sK + (n * 8 + (((ks << 2) + quad) ^ (n & 7))) * 8);
            }
            #pragma unroll
            for (int mi = 0; mi < 2; ++mi)
                #pragma unroll
                for (int nf = 0; nf < 4; ++nf)
                    sc[mi][nf] = __builtin_amdgcn_mfma_f32_16x16x32_bf16(
                        aQ[mi][ks], bK[nf], sc[mi][nf], 0, 0, 0);
        }

        #pragma unroll
        for (int mi = 0; mi < 2; ++mi)
            #pragma unroll
            for (int nf = 0; nf < 4; ++nf) {
                const int t = nf * 16 + l15;
                #pragma unroll
                for (int r = 0; r < 4; ++r) {
                    const float p = __builtin_amdgcn_exp2f(fminf(sc[mi][nf][r], 126.0f));
                    const __bf16 pb = (__bf16)p;
                    lsum[mi][r] += (float)pb;
                    const int rr = mi * 16 + quad * 4 + r;
                    sPw[(rr * 8 + ((t >> 3) ^ (rr & 7))) * 8 + (t & 7)] = pb;
                }
            }

        #pragma unroll
        for (int ks = 0; ks < 2; ++ks) {
            bf16x8 aP[2], bV[4];
            #pragma unroll
            for (int mi = 0; mi < 2; ++mi) {
                const int r = mi * 16 + l15;
                aP[mi] = *(const bf16x8*)(sPw + (r * 8 + (((ks << 2) + quad) ^ (r & 7))) * 8);
            }
            #pragma unroll
            for (int nf = 0; nf < 4; ++nf) {
                const int n = nf * 16 + l15;
                bV[nf] = *(const bf16x8*)(sV + (n * 8 + (((ks << 2) + quad) ^ (n & 7))) * 8);
            }
            #pragma unroll
            for (int mi = 0; mi < 2; ++mi)
                #pragma unroll
                for (int nf = 0; nf < 4; ++nf)
                    oacc[mi][nf] = __builtin_amdgcn_mfma_f32_16x16x32_bf16(
                        aP[mi], bV[nf], oacc[mi][nf], 0, 0, 0);
        }

        cur ^= 1;
    }

    float linv[2][4];
    #pragma unroll
    for (int mi = 0; mi < 2; ++mi)
        #pragma unroll
        for (int r = 0; r < 4; ++r) {
            float l = lsum[mi][r];
            l += __shfl_xor(l, 1, 64);
            l += __shfl_xor(l, 2, 64);
            l += __shfl_xor(l, 4, 64);
            l += __shfl_xor(l, 8, 64);
            linv[mi][r] = 1.0f / l;
        }

    #pragma unroll
    for (int mi = 0; mi < 2; ++mi)
        #pragma unroll
        for (int nf = 0; nf < 4; ++nf) {
            const int d = h * 64 + nf * 16 + l15;
            #pragma unroll
            for (int reg = 0; reg < 4; ++reg) {
                const int s = qb + mi * 16 + quad * 4 + reg;
                ctx[(size_t)(b * Sn + s) * Dm + d] =
                    (__bf16)(oacc[mi][nf][reg] * linv[mi][reg]);
            }
        }
}

// ---------------------------------------------------------------------------
extern "C" void kernel_launch(void* const* d_in, const int* in_sizes, int n_in,
                              void* d_out, int out_size, void* d_ws, size_t ws_size,
                              hipStream_t stream)
{
    const float* q  = (const float*)d_in[0];
    const float* k  = (const float*)d_in[1];
    const float* v  = (const float*)d_in[2];
    const float* Wq = (const float*)d_in[3];
    const float* bq = (const float*)d_in[4];
    const float* Wk = (const float*)d_in[5];
    const float* bk = (const float*)d_in[6];
    const float* Wv = (const float*)d_in[7];
    const float* bv = (const float*)d_in[8];
    const float* Wo = (const float*)d_in[9];
    const float* bo = (const float*)d_in[10];

    char* ws = (char*)d_ws;
    const size_t MB = 1024 * 1024;
    __bf16* qb_ = (__bf16*)(ws);            // 8 MB [4096][1024]
    __bf16* kb_ = (__bf16*)(ws + 8 * MB);
    __bf16* vb_ = (__bf16*)(ws + 16 * MB);
    __bf16* WTq = (__bf16*)(ws + 24 * MB);  // 2 MB each [N][K]
    __bf16* WTk = (__bf16*)(ws + 26 * MB);
    __bf16* WTv = (__bf16*)(ws + 28 * MB);
    __bf16* WTo = (__bf16*)(ws + 30 * MB);
    __bf16* Qh  = (__bf16*)(ws + 32 * MB);  // 8 MB [B,H,S,HD] (pre-scaled)
    __bf16* Kh  = (__bf16*)(ws + 40 * MB);  // 8 MB [B,H,S,HD]
    __bf16* Vt  = (__bf16*)(ws + 48 * MB);  // 8 MB [B,H,HD,S]
    __bf16* ctx = (__bf16*)(ws + 56 * MB);  // 8 MB [B,S,D]

    PrepArgs pa;
    pa.qkv[0] = q; pa.qkv[1] = k; pa.qkv[2] = v;
    pa.qkv_o[0] = qb_; pa.qkv_o[1] = kb_; pa.qkv_o[2] = vb_;
    pa.W[0] = Wq; pa.W[1] = Wk; pa.W[2] = Wv; pa.W[3] = Wo;
    pa.WT[0] = WTq; pa.WT[1] = WTk; pa.WT[2] = WTv; pa.WT[3] = WTo;
    pa.out_zero = (float*)d_out;
    prep_kernel<<<dim3(2048, 1, 8), 256, 0, stream>>>(pa);

    const float QSCALE = 0.0450842200f;  // log2(e) / 32

    GemmArgs qkv;
    qkv.X[0] = qb_;  qkv.X[1] = kb_;  qkv.X[2] = vb_;
    qkv.WT[0] = WTq; qkv.WT[1] = WTk; qkv.WT[2] = WTv;
    qkv.bias[0] = bq; qkv.bias[1] = bk; qkv.bias[2] = bv;
    qkv.out[0] = Qh;  qkv.out[1] = Kh;  qkv.out[2] = Vt;
    qkv.layout[0] = 0; qkv.layout[1] = 0; qkv.layout[2] = 1;
    qkv.esc[0] = QSCALE; qkv.esc[1] = 1.0f; qkv.esc[2] = 1.0f;
    gemm_bf16_kernel<<<dim3(8, 32, 3), 256, 0, stream>>>(qkv);

    flash_attn_kernel<<<dim3(8, 16, 4), 256, 0, stream>>>(Qh, Kh, Vt, ctx);

    gemm_splitk_kernel<<<dim3(8, 32, 2), 256, 0, stream>>>(
        ctx, WTo, bo, (float*)d_out);
}

// Round 9
// 231.207 us; speedup vs baseline: 1.0127x; 1.0127x over previous
//
#include <hip/hip_runtime.h>
#include <math.h>

#define Dm 1024
#define Hn 16
#define HDn 64
#define Sn 1024

typedef __attribute__((ext_vector_type(8))) __bf16 bf16x8;
typedef __attribute__((ext_vector_type(4))) float floatx4;

__device__ __forceinline__ void async_ld16(void* lds, const void* g) {
    __builtin_amdgcn_global_load_lds(
        (const __attribute__((address_space(1))) void*)g,
        (__attribute__((address_space(3))) void*)lds,
        16, 0, 0);
}

// ---------------------------------------------------------------------------
// Prep kernel. grid (2048, 1, 7), 256 thr.
//  z 0..2 : fp32->bf16 cast of q/k/v (8 elems/thread)
//  z 3..6 : W [k][n] fp32 -> WT [n][k] bf16, 64x64 tiles (x < 256)
// ---------------------------------------------------------------------------
struct PrepArgs {
    const float* qkv[3];
    __bf16*      qkv_o[3];
    const float* W[4];
    __bf16*      WT[4];
};

__global__ __launch_bounds__(256) void prep_kernel(PrepArgs a)
{
    __shared__ float sT[64][65];
    const int z = blockIdx.z, x = blockIdx.x, tid = threadIdx.x;

    if (z < 3) {
        const float* src = a.qkv[z];
        __bf16* dst = a.qkv_o[z];
        const int lin = x * 256 + tid;
        const float4 v0 = ((const float4*)src)[lin * 2];
        const float4 v1 = ((const float4*)src)[lin * 2 + 1];
        bf16x8 o;
        o[0] = (__bf16)v0.x; o[1] = (__bf16)v0.y; o[2] = (__bf16)v0.z; o[3] = (__bf16)v0.w;
        o[4] = (__bf16)v1.x; o[5] = (__bf16)v1.y; o[6] = (__bf16)v1.z; o[7] = (__bf16)v1.w;
        ((bf16x8*)dst)[lin] = o;
    } else {
        if (x >= 256) return;
        const float* W = a.W[z - 3];
        __bf16* O = a.WT[z - 3];
        const int bi = (x >> 4) * 64, bj = (x & 15) * 64;
        const int colr = tid & 63, rowg = tid >> 6;
        #pragma unroll
        for (int i = 0; i < 16; ++i) {
            const int kk = i * 4 + rowg;
            sT[kk][colr] = W[(size_t)(bi + kk) * Dm + bj + colr];
        }
        __syncthreads();
        #pragma unroll
        for (int i = 0; i < 16; ++i) {
            const int rn = i * 4 + rowg;
            O[(size_t)(bj + rn) * Dm + bi + colr] = (__bf16)sT[colr][rn];
        }
    }
}

// ---------------------------------------------------------------------------
// bf16 MFMA GEMM: 128x64 tile, BK=32 (round-3-verified staging/fragment
// pattern), 4 waves x (64x32 = 4x2 frags of 16x16x32). 12 KB LDS/block ->
// high co-residency (grid 1536 = 6 blocks/CU for QKV) to hide the
// load->barrier latency that capped the 128x128 tile at ~2.6 blocks/CU.
// XCD swizzle: xcd = id&7 owns m-group (A 1MB) x all n (B 2MB) -> 3MB in L2.
// layout 0: bf16 [B,H,S,HD]; 1: bf16 [B,H,HD,S]; 3: fp32 flat, no relu.
// ---------------------------------------------------------------------------
struct GemmArgs {
    const __bf16* X[3];
    const __bf16* WT[3];
    const float*  bias[3];
    void*         out[3];
    int   layout[3];
    float esc[3];
};

__global__ __launch_bounds__(256) void gemm_bf16_kernel(GemmArgs args)
{
    __shared__ __align__(16) __bf16 sA[128 * 32];  // 8 KB
    __shared__ __align__(16) __bf16 sB[64 * 32];   // 4 KB

    const int z = blockIdx.z;
    const __bf16* __restrict__ Xb  = args.X[z];
    const __bf16* __restrict__ WTb = args.WT[z];
    const float*  __restrict__ bias = args.bias[z];
    void* __restrict__ outp = args.out[z];
    const int layout = args.layout[z];
    const float escale = args.esc[z];

    const int tid = threadIdx.x;
    // id in [0,512): xcd = id&7 -> 4 m-tiles; (id>>3)&15 -> n; id>>7 -> m-sub
    const int id = blockIdx.x + (blockIdx.y << 4);
    const int bm = (((id & 7) << 2) | (id >> 7)) * 128;
    const int bn = ((id >> 3) & 15) * 64;

    const int lane = tid & 63;
    const int wave = tid >> 6;
    const int wm = (wave & 1) * 64;
    const int wn = (wave >> 1) * 32;
    const int l15 = lane & 15, quad = lane >> 4;

    floatx4 acc[4][2];
    #pragma unroll
    for (int mi = 0; mi < 4; ++mi)
        #pragma unroll
        for (int ni = 0; ni < 2; ++ni)
            acc[mi][ni] = (floatx4){0.f, 0.f, 0.f, 0.f};

    // staging: A 512 chunks (2/thread), B 256 chunks (1/thread)
    const int c0 = tid,       r0 = c0 >> 2, q0 = (c0 & 3) ^ (r0 & 3);
    const int c1 = tid + 256, r1 = c1 >> 2, q1 = (c1 & 3) ^ (r1 & 3);
    const int rB = tid >> 2,  qB = (tid & 3) ^ (rB & 3);
    const __bf16* gA0 = Xb  + (size_t)(bm + r0) * Dm + q0 * 8;
    const __bf16* gA1 = Xb  + (size_t)(bm + r1) * Dm + q1 * 8;
    const __bf16* gB  = WTb + (size_t)(bn + rB) * Dm + qB * 8;
    char* lA0 = (char*)sA + (tid & 192) * 16;
    char* lA1 = (char*)sA + (256 + (tid & 192)) * 16;
    char* lB  = (char*)sB + (tid & 192) * 16;

    const __bf16* fA[4];
    const __bf16* fB[2];
    #pragma unroll
    for (int mi = 0; mi < 4; ++mi) {
        const int r = wm + mi * 16 + l15;
        fA[mi] = sA + r * 32 + ((quad ^ (r & 3)) * 8);
    }
    #pragma unroll
    for (int ni = 0; ni < 2; ++ni) {
        const int r = wn + ni * 16 + l15;
        fB[ni] = sB + r * 32 + ((quad ^ (r & 3)) * 8);
    }

    for (int kt = 0; kt < Dm; kt += 32) {
        async_ld16(lA0, gA0 + kt);
        async_ld16(lA1, gA1 + kt);
        async_ld16(lB,  gB  + kt);
        __syncthreads();

        bf16x8 af[4], bfr[2];
        #pragma unroll
        for (int mi = 0; mi < 4; ++mi) af[mi] = *(const bf16x8*)fA[mi];
        #pragma unroll
        for (int ni = 0; ni < 2; ++ni) bfr[ni] = *(const bf16x8*)fB[ni];
        #pragma unroll
        for (int mi = 0; mi < 4; ++mi)
            #pragma unroll
            for (int ni = 0; ni < 2; ++ni)
                acc[mi][ni] = __builtin_amdgcn_mfma_f32_16x16x32_bf16(
                    af[mi], bfr[ni], acc[mi][ni], 0, 0, 0);
        __syncthreads();
    }

    #pragma unroll
    for (int mi = 0; mi < 4; ++mi) {
        #pragma unroll
        for (int ni = 0; ni < 2; ++ni) {
            const int n = bn + wn + ni * 16 + l15;
            const float bv = bias[n];
            const int h = n >> 6, d = n & 63;
            #pragma unroll
            for (int reg = 0; reg < 4; ++reg) {
                const int m = bm + wm + mi * 16 + quad * 4 + reg;
                const int b = m >> 10, s = m & 1023;
                if (layout == 3) {
                    ((float*)outp)[(size_t)m * 1024 + n] = acc[mi][ni][reg] + bv;
                } else {
                    float v = fmaxf(acc[mi][ni][reg] + bv, 0.0f) * escale;
                    if (layout == 0)
                        ((__bf16*)outp)[((size_t)(b * Hn + h) * 1024 + s) * 64 + d] = (__bf16)v;
                    else
                        ((__bf16*)outp)[((size_t)(b * Hn + h) * 64 + d) * 1024 + s] = (__bf16)v;
                }
            }
        }
    }
}

// ---------------------------------------------------------------------------
// Flash attention (verified): S = Q·K^T, no-max softmax (post-ReLU Q,K =>
// scores >= 0, bounded; Q pre-scaled by log2(e)/32), P via wave-private LDS,
// PV with 16x16x32 MFMA. 64-key tiles, double-buffered. XCD swizzle.
// ---------------------------------------------------------------------------
__global__ __launch_bounds__(256, 2) void flash_attn_kernel(
    const __bf16* __restrict__ Qh,  // [B,H,S,HD]  (pre-scaled by log2e/32)
    const __bf16* __restrict__ Kh,  // [B,H,S,HD]
    const __bf16* __restrict__ Vt,  // [B,H,HD,S]
    __bf16* __restrict__ ctx)       // [B,S,D]
{
    __shared__ __align__(16) char sKV[2][16384];   // per buf: K 8KB | V^T 8KB
    __shared__ __align__(16) __bf16 sP[4][32 * 64];

    const int tid = threadIdx.x;
    const int wave = tid >> 6, lane = tid & 63;
    const int l15 = lane & 15, quad = lane >> 4;

    const int id = blockIdx.x + (blockIdx.y << 3) + (blockIdx.z << 7);
    const int kk = id >> 3;
    const int bh = ((id & 7) << 3) | (kk & 7);
    const int b = bh >> 4, h = bh & 15;
    const int qb = (kk >> 3) * 128 + wave * 32;

    bf16x8 aQ[2][2];
    #pragma unroll
    for (int mi = 0; mi < 2; ++mi)
        #pragma unroll
        for (int ks = 0; ks < 2; ++ks)
            aQ[mi][ks] = *(const bf16x8*)(Qh +
                (size_t)(bh * Sn + qb + mi * 16 + l15) * 64 + ks * 32 + quad * 8);

    const int s0 = tid, s1 = tid + 256;
    const int r0 = s0 >> 3, q0c = (s0 & 7) ^ (r0 & 7);
    const int r1 = s1 >> 3, q1c = (s1 & 7) ^ (r1 & 7);
    const __bf16* gK0 = Kh + (size_t)(bh * Sn + r0) * 64 + q0c * 8;
    const __bf16* gK1 = Kh + (size_t)(bh * Sn + r1) * 64 + q1c * 8;
    const __bf16* gV0 = Vt + (size_t)(bh * 64 + r0) * Sn + q0c * 8;
    const __bf16* gV1 = Vt + (size_t)(bh * 64 + r1) * Sn + q1c * 8;
    const int wofs = (tid & 192) * 16;

    floatx4 oacc[2][4];
    #pragma unroll
    for (int mi = 0; mi < 2; ++mi)
        #pragma unroll
        for (int nf = 0; nf < 4; ++nf)
            oacc[mi][nf] = (floatx4){0.f, 0.f, 0.f, 0.f};
    float lsum[2][4];
    #pragma unroll
    for (int mi = 0; mi < 2; ++mi)
        #pragma unroll
        for (int r = 0; r < 4; ++r) lsum[mi][r] = 0.0f;

    __bf16* sPw = sP[wave];

    {
        char* bK = sKV[0];
        char* bV = sKV[0] + 8192;
        async_ld16(bK + wofs,        gK0);
        async_ld16(bK + 4096 + wofs, gK1);
        async_ld16(bV + wofs,        gV0);
        async_ld16(bV + 4096 + wofs, gV1);
    }

    int cur = 0;
    for (int it = 0; it < 16; ++it) {
        __syncthreads();

        if (it + 1 < 16) {
            const int t0n = (it + 1) * 64;
            char* bK = sKV[cur ^ 1];
            char* bV = sKV[cur ^ 1] + 8192;
            async_ld16(bK + wofs,        gK0 + (size_t)t0n * 64);
            async_ld16(bK + 4096 + wofs, gK1 + (size_t)t0n * 64);
            async_ld16(bV + wofs,        gV0 + t0n);
            async_ld16(bV + 4096 + wofs, gV1 + t0n);
        }

        const __bf16* sK = (const __bf16*)sKV[cur];
        const __bf16* sV = (const __bf16*)(sKV[cur] + 8192);

        floatx4 sc[2][4];
        #pragma unroll
        for (int mi = 0; mi < 2; ++mi)
            #pragma unroll
            for (int nf = 0; nf < 4; ++nf)
                sc[mi][nf] = (floatx4){0.f, 0.f, 0.f, 0.f};
        #pragma unroll
        for (int ks = 0; ks < 2; ++ks) {
            bf16x8 bK[4];
            #pragma unroll
            for (int nf = 0; nf < 4; ++nf) {
                const int n = nf * 16 + l15;
                bK[nf] = *(const bf16x8*)(sK + (n * 8 + (((ks << 2) + quad) ^ (n & 7))) * 8);
            }
            #pragma unroll
            for (int mi = 0; mi < 2; ++mi)
                #pragma unroll
                for (int nf = 0; nf < 4; ++nf)
                    sc[mi][nf] = __builtin_amdgcn_mfma_f32_16x16x32_bf16(
                        aQ[mi][ks], bK[nf], sc[mi][nf], 0, 0, 0);
        }

        #pragma unroll
        for (int mi = 0; mi < 2; ++mi)
            #pragma unroll
            for (int nf = 0; nf < 4; ++nf) {
                const int t = nf * 16 + l15;
                #pragma unroll
                for (int r = 0; r < 4; ++r) {
                    const float p = __builtin_amdgcn_exp2f(fminf(sc[mi][nf][r], 126.0f));
                    const __bf16 pb = (__bf16)p;
                    lsum[mi][r] += (float)pb;
                    const int rr = mi * 16 + quad * 4 + r;
                    sPw[(rr * 8 + ((t >> 3) ^ (rr & 7))) * 8 + (t & 7)] = pb;
                }
            }

        #pragma unroll
        for (int ks = 0; ks < 2; ++ks) {
            bf16x8 aP[2], bV[4];
            #pragma unroll
            for (int mi = 0; mi < 2; ++mi) {
                const int r = mi * 16 + l15;
                aP[mi] = *(const bf16x8*)(sPw + (r * 8 + (((ks << 2) + quad) ^ (r & 7))) * 8);
            }
            #pragma unroll
            for (int nf = 0; nf < 4; ++nf) {
                const int n = nf * 16 + l15;
                bV[nf] = *(const bf16x8*)(sV + (n * 8 + (((ks << 2) + quad) ^ (n & 7))) * 8);
            }
            #pragma unroll
            for (int mi = 0; mi < 2; ++mi)
                #pragma unroll
                for (int nf = 0; nf < 4; ++nf)
                    oacc[mi][nf] = __builtin_amdgcn_mfma_f32_16x16x32_bf16(
                        aP[mi], bV[nf], oacc[mi][nf], 0, 0, 0);
        }

        cur ^= 1;
    }

    float linv[2][4];
    #pragma unroll
    for (int mi = 0; mi < 2; ++mi)
        #pragma unroll
        for (int r = 0; r < 4; ++r) {
            float l = lsum[mi][r];
            l += __shfl_xor(l, 1, 64);
            l += __shfl_xor(l, 2, 64);
            l += __shfl_xor(l, 4, 64);
            l += __shfl_xor(l, 8, 64);
            linv[mi][r] = 1.0f / l;
        }

    #pragma unroll
    for (int mi = 0; mi < 2; ++mi)
        #pragma unroll
        for (int nf = 0; nf < 4; ++nf) {
            const int d = h * 64 + nf * 16 + l15;
            #pragma unroll
            for (int reg = 0; reg < 4; ++reg) {
                const int s = qb + mi * 16 + quad * 4 + reg;
                ctx[(size_t)(b * Sn + s) * Dm + d] =
                    (__bf16)(oacc[mi][nf][reg] * linv[mi][reg]);
            }
        }
}

// ---------------------------------------------------------------------------
extern "C" void kernel_launch(void* const* d_in, const int* in_sizes, int n_in,
                              void* d_out, int out_size, void* d_ws, size_t ws_size,
                              hipStream_t stream)
{
    const float* q  = (const float*)d_in[0];
    const float* k  = (const float*)d_in[1];
    const float* v  = (const float*)d_in[2];
    const float* Wq = (const float*)d_in[3];
    const float* bq = (const float*)d_in[4];
    const float* Wk = (const float*)d_in[5];
    const float* bk = (const float*)d_in[6];
    const float* Wv = (const float*)d_in[7];
    const float* bv = (const float*)d_in[8];
    const float* Wo = (const float*)d_in[9];
    const float* bo = (const float*)d_in[10];

    char* ws = (char*)d_ws;
    const size_t MB = 1024 * 1024;
    __bf16* qb_ = (__bf16*)(ws);            // 8 MB [4096][1024]
    __bf16* kb_ = (__bf16*)(ws + 8 * MB);
    __bf16* vb_ = (__bf16*)(ws + 16 * MB);
    __bf16* WTq = (__bf16*)(ws + 24 * MB);  // 2 MB each [N][K]
    __bf16* WTk = (__bf16*)(ws + 26 * MB);
    __bf16* WTv = (__bf16*)(ws + 28 * MB);
    __bf16* WTo = (__bf16*)(ws + 30 * MB);
    __bf16* Qh  = (__bf16*)(ws + 32 * MB);  // 8 MB [B,H,S,HD] (pre-scaled)
    __bf16* Kh  = (__bf16*)(ws + 40 * MB);  // 8 MB [B,H,S,HD]
    __bf16* Vt  = (__bf16*)(ws + 48 * MB);  // 8 MB [B,H,HD,S]
    __bf16* ctx = (__bf16*)(ws + 56 * MB);  // 8 MB [B,S,D]

    PrepArgs pa;
    pa.qkv[0] = q; pa.qkv[1] = k; pa.qkv[2] = v;
    pa.qkv_o[0] = qb_; pa.qkv_o[1] = kb_; pa.qkv_o[2] = vb_;
    pa.W[0] = Wq; pa.W[1] = Wk; pa.W[2] = Wv; pa.W[3] = Wo;
    pa.WT[0] = WTq; pa.WT[1] = WTk; pa.WT[2] = WTv; pa.WT[3] = WTo;
    prep_kernel<<<dim3(2048, 1, 7), 256, 0, stream>>>(pa);

    const float QSCALE = 0.0450842200f;  // log2(e) / 32

    GemmArgs qkv;
    qkv.X[0] = qb_;  qkv.X[1] = kb_;  qkv.X[2] = vb_;
    qkv.WT[0] = WTq; qkv.WT[1] = WTk; qkv.WT[2] = WTv;
    qkv.bias[0] = bq; qkv.bias[1] = bk; qkv.bias[2] = bv;
    qkv.out[0] = Qh;  qkv.out[1] = Kh;  qkv.out[2] = Vt;
    qkv.layout[0] = 0; qkv.layout[1] = 0; qkv.layout[2] = 1;
    qkv.esc[0] = QSCALE; qkv.esc[1] = 1.0f; qkv.esc[2] = 1.0f;
    gemm_bf16_kernel<<<dim3(16, 32, 3), 256, 0, stream>>>(qkv);

    flash_attn_kernel<<<dim3(8, 16, 4), 256, 0, stream>>>(Qh, Kh, Vt, ctx);

    GemmArgs og;
    og.X[0] = ctx;  og.X[1] = ctx;  og.X[2] = ctx;
    og.WT[0] = WTo; og.WT[1] = WTo; og.WT[2] = WTo;
    og.bias[0] = bo; og.bias[1] = bo; og.bias[2] = bo;
    og.out[0] = d_out; og.out[1] = d_out; og.out[2] = d_out;
    og.layout[0] = 3; og.layout[1] = 3; og.layout[2] = 3;
    og.esc[0] = 1.0f; og.esc[1] = 1.0f; og.esc[2] = 1.0f;
    gemm_bf16_kernel<<<dim3(16, 32, 1), 256, 0, stream>>>(og);
}